// Round 1
// baseline (86.552 us; speedup 1.0000x reference)
//
#include <hip/hip_runtime.h>

// Problem constants (B,T,H,D,M) = (2, 2048, 8, 64, 64), fp32 in/out.
#define BB 2
#define TT 2048
#define HH 8
#define DD 64
#define CC 128           // chunks over T
#define TC (TT / CC)     // 16 timesteps per chunk = 4 segs x 4 iters
#define NI 4             // iterations of 4 timesteps each
#define STRIDE (HH * DD) // 512 floats between consecutive timesteps
#define NBH (BB * HH)    // 16

__device__ __forceinline__ float feat(float x) {
    // elu(x) + 1 = x+1 (x>0) else exp(x)
    return x > 0.f ? x + 1.f : __expf(x);
}

__device__ __forceinline__ void feat4(float4& a) {
    a.x = feat(a.x); a.y = feat(a.y); a.z = feat(a.z); a.w = feat(a.w);
}

// Inclusive Hillis-Steele scan across the 4 seg groups (lanes ^16, ^32 up).
__device__ __forceinline__ void segscan(float4& a, int seg) {
    float u;
    u = __shfl_up(a.x, 16, 64); if (seg >= 1) a.x += u;
    u = __shfl_up(a.y, 16, 64); if (seg >= 1) a.y += u;
    u = __shfl_up(a.z, 16, 64); if (seg >= 1) a.z += u;
    u = __shfl_up(a.w, 16, 64); if (seg >= 1) a.w += u;
    u = __shfl_up(a.x, 32, 64); if (seg >= 2) a.x += u;
    u = __shfl_up(a.y, 32, 64); if (seg >= 2) a.y += u;
    u = __shfl_up(a.z, 32, 64); if (seg >= 2) a.z += u;
    u = __shfl_up(a.w, 32, 64); if (seg >= 2) a.w += u;
}

// Sum the 4 seg groups' values into every lane (butterfly over lanes ^16, ^32).
__device__ __forceinline__ void xorred4(float4& a) {
    a.x += __shfl_xor(a.x, 16, 64); a.y += __shfl_xor(a.y, 16, 64);
    a.z += __shfl_xor(a.z, 16, 64); a.w += __shfl_xor(a.w, 16, 64);
    a.x += __shfl_xor(a.x, 32, 64); a.y += __shfl_xor(a.y, 32, 64);
    a.z += __shfl_xor(a.z, 32, 64); a.w += __shfl_xor(a.w, 32, 64);
}

// Lane map: g = lane&15 -> d-group (d = 4g..4g+3), seg = lane>>4 -> timestep
// within group-of-4. One wave float4-load = 4 timesteps x 64 d = 1 KB.

// Kernel 1: per (b,h,c) chunk sums of feat(k) over the 16 timesteps.
__global__ void __launch_bounds__(64)
chunk_sums_kernel(const float* __restrict__ k, float* __restrict__ ws) {
    const int idx  = blockIdx.x;              // (b*H + h)*CC + c
    const int c    = idx & (CC - 1);
    const int h    = (idx >> 7) & (HH - 1);
    const int b    = idx >> 10;
    const int lane = threadIdx.x;
    const int g    = lane & 15;
    const int seg  = lane >> 4;

    const size_t off0 = (((size_t)b * TT + c * TC + seg) * HH + h) * DD + g * 4;
    float4 s = make_float4(0.f, 0.f, 0.f, 0.f);
    #pragma unroll
    for (int i = 0; i < NI; ++i) {
        const float4 kv = *(const float4*)(k + off0 + (size_t)(4 * i) * STRIDE);
        s.x += feat(kv.x); s.y += feat(kv.y); s.z += feat(kv.z); s.w += feat(kv.w);
    }
    xorred4(s);
    if (seg == 0)
        *(float4*)(ws + (size_t)idx * DD + g * 4) = s;
}

// Kernel 2: fused lookback-prefix + main compute. One wave per (b,h,c) chunk.
__global__ void __launch_bounds__(64)
linattn_kernel(const float* __restrict__ q, const float* __restrict__ k,
               const float* __restrict__ v, const float* __restrict__ ws,
               float* __restrict__ out) {
    const int idx  = blockIdx.x;
    const int c    = idx & (CC - 1);
    const int h    = (idx >> 7) & (HH - 1);
    const int b    = idx >> 10;
    const int lane = threadIdx.x;
    const int g    = lane & 15;
    const int seg  = lane >> 4;

    const size_t off0 = (((size_t)b * TT + c * TC + seg) * HH + h) * DD + g * 4;

    // Issue all HBM loads first (independent; overlap with the L2 lookback).
    float4 kf[NI], qf[NI], vv[NI];
    #pragma unroll
    for (int i = 0; i < NI; ++i) {
        const size_t o = off0 + (size_t)(4 * i) * STRIDE;
        kf[i] = *(const float4*)(k + o);
        qf[i] = *(const float4*)(q + o);
        vv[i] = *(const float4*)(v + o);
    }

    // Exclusive chunk carry: direct lookback over predecessors' chunk sums
    // (L2-resident: 32 KB per (b,h)). Each seg strides by 4 chunks, then
    // butterfly-reduce across segs so every lane holds carry for its 4 d's.
    const float* wsg = ws + (size_t)(idx - c) * DD + g * 4;
    float4 carry = make_float4(0.f, 0.f, 0.f, 0.f);
    for (int cp = seg; cp < c; cp += 4) {
        const float4 t = *(const float4*)(wsg + (size_t)cp * DD);
        carry.x += t.x; carry.y += t.y; carry.z += t.z; carry.w += t.w;
    }
    xorred4(carry);

    #pragma unroll
    for (int i = 0; i < NI; ++i) { feat4(kf[i]); feat4(qf[i]); }

    float4 base = carry;   // exclusive time-prefix entering iteration i
    #pragma unroll
    for (int i = 0; i < NI; ++i) {
        // ---- time cumsum per d within this group of 4 timesteps
        float4 inc = kf[i];
        segscan(inc, seg);
        float4 run;        // inclusive time-cumsum of feat(k) per d
        run.x = base.x + inc.x; run.y = base.y + inc.y;
        run.z = base.z + inc.z; run.w = base.w + inc.w;
        if (i < NI - 1) {  // add this group's total (held at seg=3, lane 48+g)
            base.x += __shfl(inc.x, 48 + g, 64);
            base.y += __shfl(inc.y, 48 + g, 64);
            base.z += __shfl(inc.z, 48 + g, 64);
            base.w += __shfl(inc.w, 48 + g, 64);
        }

        // ---- inclusive d-prefix at this timestep: in-lane prefix + g-scan
        float4 p;
        p.x = kf[i].x; p.y = p.x + kf[i].y; p.z = p.y + kf[i].z; p.w = p.z + kf[i].w;
        float cg = p.w;
        #pragma unroll
        for (int o = 1; o <= 8; o <<= 1) {
            const float u = __shfl_up(cg, o, 16);
            if (g >= o) cg += u;
        }
        const float e  = cg - p.w;   // exclusive d-prefix entering this lane
        const float sq = qf[i].x + qf[i].y + qf[i].z + qf[i].w;
        float s1 = qf[i].x * p.x + qf[i].y * p.y + qf[i].z * p.z + qf[i].w * p.w
                 + e * sq;
        float s2 = qf[i].x * run.x + qf[i].y * run.y + qf[i].z * run.z
                 + qf[i].w * run.w;
        #pragma unroll
        for (int o = 1; o <= 8; o <<= 1) {
            s1 += __shfl_xor(s1, o, 64);
            s2 += __shfl_xor(s2, o, 64);
        }

        const float r = s1 * __builtin_amdgcn_rcpf(s2);
        float4 ov;
        ov.x = vv[i].x * r; ov.y = vv[i].y * r;
        ov.z = vv[i].z * r; ov.w = vv[i].w * r;
        *(float4*)(out + off0 + (size_t)(4 * i) * STRIDE) = ov;
    }
}

extern "C" void kernel_launch(void* const* d_in, const int* in_sizes, int n_in,
                              void* d_out, int out_size, void* d_ws, size_t ws_size,
                              hipStream_t stream) {
    const float* q = (const float*)d_in[0];
    const float* k = (const float*)d_in[1];
    const float* v = (const float*)d_in[2];
    float* out = (float*)d_out;
    float* ws  = (float*)d_ws;            // needs B*H*CC*DD*4 = 512 KB

    const int nblk = BB * HH * CC;        // 2048
    chunk_sums_kernel<<<nblk, 64, 0, stream>>>(k, ws);
    linattn_kernel<<<nblk, 64, 0, stream>>>(q, k, v, ws, out);
}